// Round 12
// baseline (503.094 us; speedup 1.0000x reference)
//
#include <hip/hip_runtime.h>
#include <hip/hip_bf16.h>
#include <math.h>

#define N_NODES 20000
#define N_EDGES 320000
#define N_GRAPHS 64

typedef __bf16 bf16_t;
typedef bf16_t bf16x8 __attribute__((ext_vector_type(8)));
typedef bf16_t bf16x4 __attribute__((ext_vector_type(4)));
typedef bf16_t bf16x2 __attribute__((ext_vector_type(2)));
typedef float f32x4 __attribute__((ext_vector_type(4)));
typedef float f32x2 __attribute__((ext_vector_type(2)));

// ---------------------------------------------------------------- CSR build
__global__ void hist_k(const int* __restrict__ dst, int* __restrict__ deg, int E) {
    int e = blockIdx.x * 256 + threadIdx.x;
    if (e < E) atomicAdd(&deg[dst[e]], 1);
}

__global__ __launch_bounds__(1024) void scan_k(const int* __restrict__ deg,
                                               int* __restrict__ offs,
                                               int* __restrict__ cursor, int n) {
    __shared__ int s_ws[16];
    int tid = threadIdx.x;
    int lane = tid & 63, w = tid >> 6;
    int carry = 0;
    for (int base = 0; base < n; base += 1024) {
        int i = base + tid;
        int v = (i < n) ? deg[i] : 0;
        int x = v;
        #pragma unroll
        for (int off = 1; off < 64; off <<= 1) {
            int t = __shfl_up(x, off);
            if (lane >= off) x += t;
        }
        if (lane == 63) s_ws[w] = x;
        __syncthreads();
        if (tid < 16) {
            int y = s_ws[tid];
            #pragma unroll
            for (int off = 1; off < 16; off <<= 1) {
                int t = __shfl_up(y, off);
                if (tid >= off) y += t;
            }
            s_ws[tid] = y;
        }
        __syncthreads();
        int wbase = (w > 0) ? s_ws[w - 1] : 0;
        int ex = carry + wbase + x - v;
        if (i < n) { offs[i] = ex; cursor[i] = ex; }
        carry += s_ws[15];
        __syncthreads();
    }
    if (tid == 0) offs[n] = carry;
}

__global__ void scatter_k(const int* __restrict__ src, const int* __restrict__ dst,
                          int* __restrict__ cursor, int* __restrict__ csr_src,
                          int* __restrict__ csr_eid, int E) {
    int e = blockIdx.x * 256 + threadIdx.x;
    if (e < E) {
        int d = dst[e];
        int p = atomicAdd(&cursor[d], 1);
        csr_src[p] = src[e];
        csr_eid[p] = e;
    }
}

// --------------------------------------------- weight transpose + bf16 cast
__global__ __launch_bounds__(256) void wt_k(const float* __restrict__ W,
                                            bf16_t* __restrict__ Bt, int K, int N) {
    __shared__ float t[32][33];
    int k0 = blockIdx.y * 32, n0 = blockIdx.x * 32;
    int tx = threadIdx.x & 31, ty = threadIdx.x >> 5;
    for (int i = ty; i < 32; i += 8) t[i][tx] = W[(size_t)(k0 + i) * N + n0 + tx];
    __syncthreads();
    for (int i = ty; i < 32; i += 8)
        Bt[(size_t)(n0 + i) * K + k0 + tx] = (bf16_t)t[tx][i];
}

// ---- layer-3 fused weight: Bt[n][k] (128 x 1792), k<1536: stacked W3/6; else lw3
__global__ void w3s_k(const float* __restrict__ W3, const float* __restrict__ lw3,
                      bf16_t* __restrict__ Bt) {
    int id = blockIdx.x * 256 + threadIdx.x;  // 128*1792 = 229376 -> 896 blocks
    if (id >= 128 * 1792) return;
    int n = id / 1792, k = id - n * 1792;
    float v;
    if (k < 1536) {
        int h = k >> 8, c = k & 255;
        v = W3[(size_t)c * 768 + h * 128 + n] * (1.f / 6.f);
    } else {
        int c = k - 1536;
        v = lw3[(size_t)c * 128 + n];
    }
    Bt[id] = (bf16_t)v;
}

// ---- layer-1 fused weight B (40 x 256, f32): block-diag W1 per head + lw1
__global__ void b40_k(const float* __restrict__ W1, const float* __restrict__ lw1,
                      float* __restrict__ B) {
    int id = blockIdx.x * 256 + threadIdx.x;  // 40*256 = 10240 -> 40 blocks
    if (id >= 40 * 256) return;
    int k = id >> 8, n = id & 255;
    float v;
    if (k < 32) {
        int h = k >> 3, c = k & 7;
        v = ((n >> 6) == h) ? W1[(size_t)c * 256 + n] : 0.f;
    } else {
        int c = k - 32;
        v = lw1[(size_t)c * 256 + n];
    }
    B[id] = v;
}

// ---- folded attention vectors: Va[k][h] = sum_c W[k][h*C+c] * a_s[h][c]
__global__ void va_k(const float* __restrict__ W, const float* __restrict__ a_s,
                     const float* __restrict__ a_d, float* __restrict__ Va,
                     float* __restrict__ Vd, int H, int C) {
    int k = blockIdx.x;
    int lane = threadIdx.x;  // 64
    const float* wr = W + (size_t)k * H * C;
    for (int h = 0; h < H; ++h) {
        float sa = 0.f, sd = 0.f;
        for (int c = lane; c < C; c += 64) {
            float wv = wr[h * C + c];
            sa += wv * a_s[h * C + c];
            sd += wv * a_d[h * C + c];
        }
        #pragma unroll
        for (int m = 32; m; m >>= 1) { sa += __shfl_xor(sa, m); sd += __shfl_xor(sd, m); }
        if (lane == 0) { Va[k * H + h] = sa; Vd[k * H + h] = sd; }
    }
}

__global__ void addb_k(const float* __restrict__ a, const float* __restrict__ b,
                       float* __restrict__ o, int n) {
    int i = blockIdx.x * 256 + threadIdx.x;
    if (i < n) o[i] = a[i] + b[i];
}

// ---------------------------------------------------------------- fp32 GEMM
template <typename OUT>
__global__ __launch_bounds__(256) void gemm_k(const float* __restrict__ A,
                                              const float* __restrict__ B,
                                              OUT* __restrict__ C,
                                              const float* __restrict__ bias,
                                              int M, int N, int K, int relu) {
    __shared__ float As[16][65];
    __shared__ float Bs[16][64];
    int tid = threadIdx.x;
    int tx = tid & 15, ty = tid >> 4;
    int row0 = blockIdx.y * 64, col0 = blockIdx.x * 64;
    float acc[4][4] = {};
    for (int k0 = 0; k0 < K; k0 += 16) {
        #pragma unroll
        for (int i = 0; i < 4; ++i) {
            int idx = tid + i * 256;
            int m = idx >> 4, kk = idx & 15;
            int gm = row0 + m, gk = k0 + kk;
            As[kk][m] = (gm < M && gk < K) ? A[(size_t)gm * K + gk] : 0.f;
        }
        #pragma unroll
        for (int i = 0; i < 4; ++i) {
            int idx = tid + i * 256;
            int kk = idx >> 6, n = idx & 63;
            int gk = k0 + kk, gn = col0 + n;
            Bs[kk][n] = (gk < K && gn < N) ? B[(size_t)gk * N + gn] : 0.f;
        }
        __syncthreads();
        #pragma unroll
        for (int kk = 0; kk < 16; ++kk) {
            float a[4], b[4];
            #pragma unroll
            for (int i = 0; i < 4; ++i) a[i] = As[kk][ty * 4 + i];
            #pragma unroll
            for (int j = 0; j < 4; ++j) b[j] = Bs[kk][tx * 4 + j];
            #pragma unroll
            for (int i = 0; i < 4; ++i)
                #pragma unroll
                for (int j = 0; j < 4; ++j) acc[i][j] += a[i] * b[j];
        }
        __syncthreads();
    }
    #pragma unroll
    for (int i = 0; i < 4; ++i) {
        int gm = row0 + ty * 4 + i;
        if (gm >= M) continue;
        #pragma unroll
        for (int j = 0; j < 4; ++j) {
            int gn = col0 + tx * 4 + j;
            if (gn < N) {
                float r = acc[i][j] + (bias ? bias[gn] : 0.f);
                if (relu) r = fmaxf(r, 0.f);
                C[(size_t)gm * N + gn] = (OUT)r;
            }
        }
    }
}

// ------------------------------------------------------------ bf16 MFMA GEMM
// Optional fused attention-score epilogue (Ch==64: wave half = one head).
template <typename OUT>
__global__ __launch_bounds__(256) void gemm_bf16_k(
    const bf16_t* __restrict__ A, const bf16_t* __restrict__ Bt,
    OUT* __restrict__ C, const float* __restrict__ bias, int M, int N, int K,
    const float* __restrict__ asv, const float* __restrict__ adv,
    float* __restrict__ as_o, float* __restrict__ ad_o, int H, int Ch, int relu) {
    __shared__ bf16_t As[128][40];
    __shared__ bf16_t Bs[128][40];
    int tid = threadIdx.x;
    int row0 = blockIdx.y * 128, col0 = blockIdx.x * 128;
    int wave = tid >> 6, lane = tid & 63, quad = lane >> 4, l16 = lane & 15;
    int wm = wave >> 1, wn = wave & 1;
    f32x4 acc[4][4] = {};
    int sr = tid >> 2;
    int sc = (tid & 3) * 8;
    for (int k0 = 0; k0 < K; k0 += 32) {
        #pragma unroll
        for (int half = 0; half < 2; ++half) {
            int r = sr + half * 64;
            int gm = row0 + r;
            bf16x8 v = {};
            if (gm < M) v = *(const bf16x8*)&A[(size_t)gm * K + k0 + sc];
            *(bf16x8*)&As[r][sc] = v;
            int gn = col0 + r;
            bf16x8 w = {};
            if (gn < N) w = *(const bf16x8*)&Bt[(size_t)gn * K + k0 + sc];
            *(bf16x8*)&Bs[r][sc] = w;
        }
        __syncthreads();
        bf16x8 af[4], bfr[4];
        #pragma unroll
        for (int i = 0; i < 4; ++i) {
            af[i] = *(const bf16x8*)&As[wm * 64 + i * 16 + l16][quad * 8];
            bfr[i] = *(const bf16x8*)&Bs[wn * 64 + i * 16 + l16][quad * 8];
        }
        #pragma unroll
        for (int i = 0; i < 4; ++i)
            #pragma unroll
            for (int j = 0; j < 4; ++j)
                acc[i][j] = __builtin_amdgcn_mfma_f32_16x16x32_bf16(af[i], bfr[j],
                                                                   acc[i][j], 0, 0, 0);
        __syncthreads();
    }
    #pragma unroll
    for (int i = 0; i < 4; ++i) {
        int base_m = row0 + wm * 64 + i * 16 + quad * 4;
        #pragma unroll
        for (int j = 0; j < 4; ++j) {
            int gn = col0 + wn * 64 + j * 16 + l16;
            float bv = bias ? bias[gn] : 0.f;
            #pragma unroll
            for (int r = 0; r < 4; ++r) {
                int gm = base_m + r;
                if (gm < M) {
                    float rr = acc[i][j][r] + bv;
                    if (relu) rr = fmaxf(rr, 0.f);
                    C[(size_t)gm * N + gn] = (OUT)rr;
                }
            }
        }
    }
    if (asv) {
        int hd = (col0 + wn * 64) / Ch;
        float av[4], dv[4];
        #pragma unroll
        for (int j = 0; j < 4; ++j) {
            int ca = col0 + wn * 64 + j * 16 + l16;
            av[j] = asv[ca];
            dv[j] = adv[ca];
        }
        #pragma unroll
        for (int i = 0; i < 4; ++i) {
            float sp[4] = {}, sd[4] = {};
            #pragma unroll
            for (int j = 0; j < 4; ++j)
                #pragma unroll
                for (int r = 0; r < 4; ++r) {
                    sp[r] += acc[i][j][r] * av[j];
                    sd[r] += acc[i][j][r] * dv[j];
                }
            #pragma unroll
            for (int m = 1; m < 16; m <<= 1)
                #pragma unroll
                for (int r = 0; r < 4; ++r) {
                    sp[r] += __shfl_xor(sp[r], m);
                    sd[r] += __shfl_xor(sd[r], m);
                }
            if (l16 == 0) {
                #pragma unroll
                for (int r = 0; r < 4; ++r) {
                    int gm = row0 + wm * 64 + i * 16 + quad * 4 + r;
                    if (gm < M) {
                        as_o[gm * H + hd] = sp[r];
                        ad_o[gm * H + hd] = sd[r];
                    }
                }
            }
        }
    }
}

// ----------------- thin-N bf16 MFMA GEMM: BM=32, BN=64, direct write + relu
__global__ __launch_bounds__(256) void gemm_bf16_thin_k(
    const bf16_t* __restrict__ A, const bf16_t* __restrict__ Bt,
    float* __restrict__ C, const float* __restrict__ bias, int M, int N, int K) {
    __shared__ bf16_t As[32][40];
    __shared__ bf16_t Bs[64][40];
    int tid = threadIdx.x;
    int row0 = blockIdx.y * 32, col0 = blockIdx.x * 64;
    int wave = tid >> 6, lane = tid & 63, quad = lane >> 4, l16 = lane & 15;
    int wr = wave & 1;          // row-tile 0/1 (16 rows each)
    int wc = wave >> 1;         // col-half 0/1 (32 cols each)
    f32x4 acc[2] = {};
    int ar = tid >> 2, ac = (tid & 3) * 8;   // staging coords
    for (int k0 = 0; k0 < K; k0 += 32) {
        if (tid < 128) {
            int gm = row0 + ar;
            bf16x8 v = {};
            if (gm < M) v = *(const bf16x8*)&A[(size_t)gm * K + k0 + ac];
            *(bf16x8*)&As[ar][ac] = v;
        }
        *(bf16x8*)&Bs[ar][ac] = *(const bf16x8*)&Bt[(size_t)(col0 + ar) * K + k0 + ac];
        __syncthreads();
        bf16x8 af = *(const bf16x8*)&As[wr * 16 + l16][quad * 8];
        #pragma unroll
        for (int j = 0; j < 2; ++j) {
            bf16x8 bf = *(const bf16x8*)&Bs[wc * 32 + j * 16 + l16][quad * 8];
            acc[j] = __builtin_amdgcn_mfma_f32_16x16x32_bf16(af, bf, acc[j], 0, 0, 0);
        }
        __syncthreads();
    }
    #pragma unroll
    for (int j = 0; j < 2; ++j) {
        int gn = col0 + wc * 32 + j * 16 + l16;
        float bv = bias[gn];
        #pragma unroll
        for (int r = 0; r < 4; ++r) {
            int gm = row0 + wr * 16 + quad * 4 + r;
            if (gm < M) C[(size_t)gm * N + gn] = fmaxf(acc[j][r] + bv, 0.f);
        }
    }
}

__device__ __forceinline__ float leaky02(float v) { return v > 0.f ? v : 0.2f * v; }

// ------------------------------- layer-1 scores: as[j][h] = x[j]·Va1[:,h]
__global__ void asad1_k(const float* __restrict__ x, const float* __restrict__ Va,
                        const float* __restrict__ Vd, float* __restrict__ as_,
                        float* __restrict__ ad_, int N) {
    int idx = blockIdx.x * 256 + threadIdx.x;
    if (idx >= N * 4) return;
    int j = idx >> 2, h = idx & 3;
    const float* xr = x + (size_t)j * 8;
    float sa = 0.f, sd = 0.f;
    #pragma unroll
    for (int c = 0; c < 8; ++c) {
        sa += xr[c] * Va[c * 4 + h];
        sd += xr[c] * Vd[c * 4 + h];
    }
    as_[idx] = sa;
    ad_[idx] = sd;
}

// ------------------------------- layer-3 scores: as[j][h] = xb[j]·Va3[:,h]
__global__ void asad3_k(const bf16_t* __restrict__ xb, const float* __restrict__ Va,
                        const float* __restrict__ Vd, float* __restrict__ as_,
                        float* __restrict__ ad_) {
    int j = blockIdx.x;
    int lane = threadIdx.x;  // 64
    bf16x4 v = *(const bf16x4*)&xb[(size_t)j * 256 + lane * 4];
    float sa[6] = {}, sd[6] = {};
    #pragma unroll
    for (int i = 0; i < 4; ++i) {
        int k = lane * 4 + i;
        float xv = (float)v[i];
        #pragma unroll
        for (int h = 0; h < 6; ++h) {
            sa[h] += xv * Va[k * 6 + h];
            sd[h] += xv * Vd[k * 6 + h];
        }
    }
    #pragma unroll
    for (int h = 0; h < 6; ++h) {
        float a = sa[h], d = sd[h];
        #pragma unroll
        for (int m = 32; m; m >>= 1) { a += __shfl_xor(a, m); d += __shfl_xor(d, m); }
        if (lane == 0) { as_[j * 6 + h] = a; ad_[j * 6 + h] = d; }
    }
}

// ---------------- layer-1 aggregation in input space (8 ch, 4 heads) -> z1[40]
__global__ __launch_bounds__(256) void agg_z1_k(
    const float* __restrict__ x, const float* __restrict__ as_,
    const float* __restrict__ ad_, const int* __restrict__ offs,
    const int* __restrict__ csr_src, float* __restrict__ z1) {
    int j = blockIdx.x * 4 + (threadIdx.x >> 6);
    int t = threadIdx.x & 63;
    int e_l = t >> 3, c = t & 7;
    int o0 = offs[j], deg = offs[j + 1] - o0;
    float adj0 = ad_[j * 4 + 0], adj1 = ad_[j * 4 + 1];
    float adj2 = ad_[j * 4 + 2], adj3 = ad_[j * 4 + 3];
    float acc[4] = {}, ws[4] = {};
    for (int e0 = 0; e0 < deg; e0 += 8) {
        int ne = min(8, deg - e0);
        if (e_l < ne) {
            int s = csr_src[o0 + e0 + e_l];
            float xv = x[(size_t)s * 8 + c];
            f32x4 a = *(const f32x4*)&as_[s * 4];
            float w0 = __expf(leaky02(a[0] + adj0));
            float w1 = __expf(leaky02(a[1] + adj1));
            float w2 = __expf(leaky02(a[2] + adj2));
            float w3 = __expf(leaky02(a[3] + adj3));
            acc[0] += w0 * xv; acc[1] += w1 * xv;
            acc[2] += w2 * xv; acc[3] += w3 * xv;
            ws[0] += w0; ws[1] += w1; ws[2] += w2; ws[3] += w3;
        }
    }
    #pragma unroll
    for (int m = 8; m < 64; m <<= 1)
        #pragma unroll
        for (int h = 0; h < 4; ++h) {
            acc[h] += __shfl_xor(acc[h], m);
            ws[h] += __shfl_xor(ws[h], m);
        }
    if (e_l == 0) {
        #pragma unroll
        for (int h = 0; h < 4; ++h)
            z1[(size_t)j * 40 + h * 8 + c] = acc[h] / (ws[h] + 1e-16f);
        z1[(size_t)j * 40 + 32 + c] = x[(size_t)j * 8 + c];
    }
}

// ------------------------------------------- aggregation, concat (H=4,C=64)
// (layer 2 only) single-pass no-max softmax, 8 edge-groups x 32 chunk-threads.
__global__ __launch_bounds__(256) void agg_concat_k(
    const bf16_t* __restrict__ h, const float* __restrict__ as_,
    const float* __restrict__ ad_, const int* __restrict__ offs,
    const int* __restrict__ csr_src, const float* __restrict__ lin,
    const float* __restrict__ bgat, bf16_t* __restrict__ xb) {
    int j = blockIdx.x;
    int tid = threadIdx.x;  // 256
    int o0 = offs[j], deg = offs[j + 1] - o0;
    __shared__ int s_src[64];
    __shared__ float s_adj[4];
    __shared__ float s_ws[8][4];
    __shared__ float s_inv[4];
    __shared__ float s_red[8][256];
    if (tid < 4) s_adj[tid] = ad_[j * 4 + tid];
    int g = tid >> 5;
    int u = tid & 31;
    int myh = u >> 3;
    const char* hbase = (const char*)h + u * 16;
    f32x4 acc0 = {}, acc1 = {};
    float wsum = 0.f;
    for (int e0 = 0; e0 < deg; e0 += 64) {
        int ne = min(64, deg - e0);
        if (tid < ne) s_src[tid] = csr_src[o0 + e0 + tid];
        __syncthreads();
        float adj = s_adj[myh];
        #pragma unroll 2
        for (int e = g; e < ne; e += 8) {
            int s = s_src[e];
            float w = __expf(leaky02(as_[s * 4 + myh] + adj));
            bf16x8 v = *(const bf16x8*)(hbase + (size_t)s * 512);
            wsum += w;
            #pragma unroll
            for (int i = 0; i < 4; ++i) acc0[i] += w * (float)v[i];
            #pragma unroll
            for (int i = 0; i < 4; ++i) acc1[i] += w * (float)v[4 + i];
        }
        __syncthreads();
    }
    if ((u & 7) == 0) s_ws[g][myh] = wsum;
    *(f32x4*)&s_red[g][u * 8] = acc0;
    *(f32x4*)&s_red[g][u * 8 + 4] = acc1;
    __syncthreads();
    if (tid < 4) {
        float d = 0.f;
        #pragma unroll
        for (int g2 = 0; g2 < 8; ++g2) d += s_ws[g2][tid];
        s_inv[tid] = 1.f / (d + 1e-16f);
    }
    __syncthreads();
    {
        int c = tid;
        float s = 0.f;
        #pragma unroll
        for (int g2 = 0; g2 < 8; ++g2) s += s_red[g2][c];
        float v = fmaxf(s * s_inv[c >> 6] + bgat[c] + lin[(size_t)j * 256 + c], 0.f);
        xb[(size_t)j * 256 + c] = (bf16_t)v;
    }
}

// --------- layer-3 aggregation via MFMA: z_h = W(6xdeg)·X(degx256) per node.
// Per 32-edge chunk: stage gathered xb rows TRANSPOSED into s_XT[256][34]
// (B-operand wants [n][k]); w as bf16 in s_wb[16][32] (A-operand [m][k],
// rows 6..15 and tail edges zeroed). 4 waves x 4 N-tiles, frag layouts
// identical to gemm_bf16_k. wsum stays f32 for exact normalization.
__global__ __launch_bounds__(256) void agg_z3_k(
    const bf16_t* __restrict__ xb, const float* __restrict__ as_,
    const float* __restrict__ ad_, const int* __restrict__ offs,
    const int* __restrict__ csr_src, const int* __restrict__ csr_eid,
    bf16_t* __restrict__ z, float* __restrict__ att) {
    int j = blockIdx.x;
    int tid = threadIdx.x;  // 256
    int o0 = offs[j], deg = offs[j + 1] - o0;
    __shared__ float s_adj[6];
    __shared__ int s_src[32];
    __shared__ bf16_t s_wb[16][32];    // A: [h][e]
    __shared__ bf16_t s_XT[256][34];   // B: [ch][e], +2 pad (odd 17-dword rows)
    __shared__ float s_wp[192];
    __shared__ float s_inv[6];
    if (tid < 6) s_adj[tid] = ad_[j * 6 + tid];
    int wave = tid >> 6, lane = tid & 63, quad = lane >> 4, l16 = lane & 15;
    int we = tid / 6, wh = tid - we * 6;        // w-phase: (edge, head), tid<192
    int se = tid >> 3, scp = tid & 7;           // staging: edge, chunk-part
    f32x4 acc[4] = {};
    float wrun = 0.f;
    __syncthreads();
    for (int e0 = 0; e0 < deg; e0 += 32) {
        int ne = min(32, deg - e0);
        // phase A: load srcs + zero s_wb
        if (tid < 32) s_src[tid] = (tid < ne) ? csr_src[o0 + e0 + tid] : -1;
        if (tid >= 64 && tid < 128) {
            f32x4 zz = {};
            *(f32x4*)((char*)s_wb + (tid - 64) * 16) = zz;
        }
        __syncthreads();
        // phase B: w (f32 sum + bf16 store) and transposed staging
        if (tid < 192 && we < ne) {
            int s = s_src[we];
            float w = __expf(leaky02(as_[s * 6 + wh] + s_adj[wh]));
            wrun += w;
            s_wb[wh][we] = (bf16_t)w;
        }
        {
            int s2 = s_src[se];
            #pragma unroll
            for (int i = 0; i < 4; ++i) {
                int ch0 = (scp * 4 + i) * 8;
                bf16x8 v = {};
                if (s2 >= 0) v = *(const bf16x8*)&xb[(size_t)s2 * 256 + ch0];
                #pragma unroll
                for (int q = 0; q < 8; ++q) s_XT[ch0 + q][se] = v[q];
            }
        }
        __syncthreads();
        // phase C: MFMA — wave handles N-tiles 4*wave .. 4*wave+3
        bf16x8 af = *(const bf16x8*)&s_wb[l16][quad * 8];
        #pragma unroll
        for (int tn = 0; tn < 4; ++tn) {
            int n0 = (wave * 4 + tn) * 16;
            bf16x8 bf = *(const bf16x8*)&s_XT[n0 + l16][quad * 8];
            acc[tn] = __builtin_amdgcn_mfma_f32_16x16x32_bf16(af, bf, acc[tn], 0, 0, 0);
        }
        __syncthreads();
    }
    if (tid < 192) s_wp[tid] = wrun;
    __syncthreads();
    if (tid < 6) {
        float d = 0.f;
        #pragma unroll
        for (int k = 0; k < 32; ++k) d += s_wp[k * 6 + tid];
        s_inv[tid] = 1.f / (d + 1e-16f);
    }
    __syncthreads();
    // write z_h: D layout col=lane&15, row=quad*4+r; valid h<6
    if (quad < 2) {
        #pragma unroll
        for (int tn = 0; tn < 4; ++tn) {
            int n0 = (wave * 4 + tn) * 16;
            #pragma unroll
            for (int r = 0; r < 4; ++r) {
                int h = quad * 4 + r;
                if (h < 6)
                    z[(size_t)j * 1792 + h * 256 + n0 + l16] =
                        (bf16_t)(acc[tn][r] * s_inv[h]);
            }
        }
    }
    if (tid < 32)
        *(bf16x8*)&z[(size_t)j * 1792 + 1536 + tid * 8] =
            *(const bf16x8*)&xb[(size_t)j * 256 + tid * 8];
    for (int idx = tid; idx < deg * 6; idx += 256) {
        int e = idx / 6, hh = idx - e * 6;
        int p = o0 + e;
        int s = csr_src[p];
        att[(size_t)csr_eid[p] * 6 + hh] =
            __expf(leaky02(as_[s * 6 + hh] + s_adj[hh])) * s_inv[hh];
    }
}

// ---------------------------------------------------------------- BatchNorm
__global__ void bn_stats_k(const float* __restrict__ y, float* __restrict__ sums, int N) {
    int c = threadIdx.x;  // 128
    float s = 0.f, q = 0.f;
    for (int r = blockIdx.x; r < N; r += gridDim.x) {
        float v = y[(size_t)r * 128 + c];
        s += v;
        q += v * v;
    }
    atomicAdd(&sums[c], s);
    atomicAdd(&sums[128 + c], q);
}
__global__ void bn_scale_k(const float* __restrict__ sums, const float* __restrict__ gamma,
                           const float* __restrict__ beta, float* __restrict__ scale,
                           float* __restrict__ shift, int N) {
    int c = threadIdx.x;
    float mu = sums[c] / (float)N;
    float var = fmaxf(sums[128 + c] / (float)N - mu * mu, 0.f);
    float inv = rsqrtf(var + 1e-5f) * gamma[c];
    scale[c] = inv;
    shift[c] = beta[c] - mu * inv;
}

// ---------------------------------------------------------------- max pool
__device__ __forceinline__ unsigned f2key(float f) {
    unsigned b = __float_as_uint(f);
    return (b & 0x80000000u) ? ~b : (b | 0x80000000u);
}
__global__ void pool_init_k(unsigned* __restrict__ pool_u) {
    int i = blockIdx.x * 256 + threadIdx.x;
    if (i < N_GRAPHS * 128) pool_u[i] = f2key(-3.402823466e38f * 2.0f);
}
__global__ void norm_pool_k(const float* __restrict__ y, const float* __restrict__ scale,
                            const float* __restrict__ shift, const int* __restrict__ batch,
                            unsigned* __restrict__ pool_u, int N) {
    int idx = blockIdx.x * 256 + threadIdx.x;
    if (idx >= N * 128) return;
    int n = idx >> 7, c = idx & 127;
    float v = y[idx] * scale[c] + shift[c];
    atomicMax(&pool_u[batch[n] * 128 + c], f2key(v));
}
__global__ void pool_write_k(const unsigned* __restrict__ pool_u, float* __restrict__ out) {
    int i = blockIdx.x * 256 + threadIdx.x;
    if (i < N_GRAPHS * 128) {
        unsigned u = pool_u[i];
        unsigned b = (u & 0x80000000u) ? (u & 0x7FFFFFFFu) : ~u;
        out[i] = __uint_as_float(b);
    }
}

// ================================================================ launcher
extern "C" void kernel_launch(void* const* d_in, const int* in_sizes, int n_in,
                              void* d_out, int out_size, void* d_ws, size_t ws_size,
                              hipStream_t stream) {
    const int N = N_NODES, E = N_EDGES;
    const float* x_ppi = (const float*)d_in[0];
    const int* edge = (const int*)d_in[1];
    const int* batch = (const int*)d_in[2];
    const float* W1 = (const float*)d_in[3];
    const float* a_src1 = (const float*)d_in[4];
    const float* a_dst1 = (const float*)d_in[5];
    const float* b_gat1 = (const float*)d_in[6];
    const float* lw1 = (const float*)d_in[7];
    const float* lb1 = (const float*)d_in[8];
    const float* W2 = (const float*)d_in[9];
    const float* a_src2 = (const float*)d_in[10];
    const float* a_dst2 = (const float*)d_in[11];
    const float* b_gat2 = (const float*)d_in[12];
    const float* lw2 = (const float*)d_in[13];
    const float* lb2 = (const float*)d_in[14];
    const float* W3 = (const float*)d_in[15];
    const float* a_src3 = (const float*)d_in[16];
    const float* a_dst3 = (const float*)d_in[17];
    const float* b_gat3 = (const float*)d_in[18];
    const float* lw3 = (const float*)d_in[19];
    const float* lb3 = (const float*)d_in[20];
    const float* bn_gamma = (const float*)d_in[21];
    const float* bn_beta = (const float*)d_in[22];

    const int* src = edge;
    const int* dst = edge + E;

    size_t off = 0;
    auto alloc = [&](size_t bytes) {
        size_t o = off;
        off = (off + bytes + 255) & ~(size_t)255;
        return o;
    };
    char* ws = (char*)d_ws;
    bf16_t* xb = (bf16_t*)(ws + alloc((size_t)N * 256 * 2));
    bf16_t* zbig = (bf16_t*)(ws + alloc((size_t)N * 1792 * 2)); // union: hb (layer2) / z3
    bf16_t* hb = zbig;
    bf16_t* z3 = zbig;
    float* lin = (float*)(ws + alloc((size_t)N * 256 * 4));      // layer-2 lin; reused as y
    float* z1 = (float*)(ws + alloc((size_t)N * 40 * 4));
    float* as_ = (float*)(ws + alloc((size_t)N * 6 * 4));
    float* ad_ = (float*)(ws + alloc((size_t)N * 6 * 4));
    int* deg = (int*)(ws + alloc((size_t)(N + 1) * 4));
    int* offs = (int*)(ws + alloc((size_t)(N + 1) * 4));
    int* cursor = (int*)(ws + alloc((size_t)(N + 1) * 4));
    int* csr_src = (int*)(ws + alloc((size_t)E * 4));
    int* csr_eid = (int*)(ws + alloc((size_t)E * 4));
    bf16_t* Wt2 = (bf16_t*)(ws + alloc((size_t)256 * 256 * 2));
    bf16_t* lwt2 = (bf16_t*)(ws + alloc((size_t)256 * 256 * 2));
    bf16_t* Bt3s = (bf16_t*)(ws + alloc((size_t)128 * 1792 * 2));
    float* B40 = (float*)(ws + alloc((size_t)40 * 256 * 4));
    float* Va1 = (float*)(ws + alloc(8 * 4 * 4));
    float* Vd1 = (float*)(ws + alloc(8 * 4 * 4));
    float* Va3 = (float*)(ws + alloc(256 * 6 * 4));
    float* Vd3 = (float*)(ws + alloc(256 * 6 * 4));
    float* bias1s = (float*)(ws + alloc(256 * 4));
    float* bias3s = (float*)(ws + alloc(128 * 4));
    float* bn_sums = (float*)(ws + alloc(256 * 4));
    float* bn_scale = (float*)(ws + alloc(128 * 4));
    float* bn_shift = (float*)(ws + alloc(128 * 4));
    unsigned* pool_u = (unsigned*)(ws + alloc((size_t)N_GRAPHS * 128 * 4));

    float* out_pool = (float*)d_out;
    float* out_att = (float*)d_out + N_GRAPHS * 128;

    // ---- CSR + weight prep (independent)
    hipMemsetAsync(deg, 0, (size_t)N * 4, stream);
    hist_k<<<(E + 255) / 256, 256, 0, stream>>>(dst, deg, E);
    scan_k<<<1, 1024, 0, stream>>>(deg, offs, cursor, N);
    scatter_k<<<(E + 255) / 256, 256, 0, stream>>>(src, dst, cursor, csr_src, csr_eid, E);
    wt_k<<<dim3(8, 8), 256, 0, stream>>>(W2, Wt2, 256, 256);
    wt_k<<<dim3(8, 8), 256, 0, stream>>>(lw2, lwt2, 256, 256);
    w3s_k<<<896, 256, 0, stream>>>(W3, lw3, Bt3s);
    b40_k<<<40, 256, 0, stream>>>(W1, lw1, B40);
    va_k<<<8, 64, 0, stream>>>(W1, a_src1, a_dst1, Va1, Vd1, 4, 64);
    va_k<<<256, 64, 0, stream>>>(W3, a_src3, a_dst3, Va3, Vd3, 6, 128);
    addb_k<<<1, 256, 0, stream>>>(lb1, b_gat1, bias1s, 256);
    addb_k<<<1, 128, 0, stream>>>(lb3, b_gat3, bias3s, 128);

    // ---- Layer 1: aggregate in 8-ch input space, then one K=40 fused GEMM
    asad1_k<<<(N * 4 + 255) / 256, 256, 0, stream>>>(x_ppi, Va1, Vd1, as_, ad_, N);
    agg_z1_k<<<N / 4, 256, 0, stream>>>(x_ppi, as_, ad_, offs, csr_src, z1);
    gemm_k<bf16_t><<<dim3(4, 313), 256, 0, stream>>>(z1, B40, xb, bias1s, N, 256, 40, 1);

    // ---- Layer 2 (256 -> 256, bf16 MFMA); as/ad fused into h-GEMM epilogue
    gemm_bf16_k<bf16_t><<<dim3(2, 157), 256, 0, stream>>>(xb, Wt2, hb, nullptr, N, 256, 256,
                                                          a_src2, a_dst2, as_, ad_, 4, 64, 0);
    gemm_bf16_k<float><<<dim3(2, 157), 256, 0, stream>>>(xb, lwt2, lin, lb2, N, 256, 256,
                                                         nullptr, nullptr, nullptr, nullptr,
                                                         0, 1, 0);
    agg_concat_k<<<N, 256, 0, stream>>>(hb, as_, ad_, offs, csr_src, lin, b_gat2, xb);

    // ---- Layer 3: scores from folded Va3/Vd3, MFMA aggregation, thin GEMM
    float* y = lin;  // reuse (free after agg_concat_k)
    asad3_k<<<N, 64, 0, stream>>>(xb, Va3, Vd3, as_, ad_);
    agg_z3_k<<<N, 256, 0, stream>>>(xb, as_, ad_, offs, csr_src, csr_eid, z3, out_att);
    gemm_bf16_thin_k<<<dim3(2, 625), 256, 0, stream>>>(z3, Bt3s, y, bias3s, N, 128, 1792);

    // ---- BatchNorm (training stats, fused sum+sumsq pass)
    hipMemsetAsync(bn_sums, 0, 256 * 4, stream);
    bn_stats_k<<<160, 128, 0, stream>>>(y, bn_sums, N);
    bn_scale_k<<<1, 128, 0, stream>>>(bn_sums, bn_gamma, bn_beta, bn_scale, bn_shift, N);

    // ---- normalize + global max pool
    pool_init_k<<<(N_GRAPHS * 128 + 255) / 256, 256, 0, stream>>>(pool_u);
    norm_pool_k<<<((size_t)N * 128 + 255) / 256, 256, 0, stream>>>(y, bn_scale, bn_shift, batch,
                                                                   pool_u, N);
    pool_write_k<<<(N_GRAPHS * 128 + 255) / 256, 256, 0, stream>>>(pool_u, out_pool);
}

// Round 14
// 457.408 us; speedup vs baseline: 1.0999x; 1.0999x over previous
//
#include <hip/hip_runtime.h>
#include <hip/hip_bf16.h>
#include <math.h>

#define N_NODES 20000
#define N_EDGES 320000
#define N_GRAPHS 64

typedef __bf16 bf16_t;
typedef bf16_t bf16x8 __attribute__((ext_vector_type(8)));
typedef bf16_t bf16x4 __attribute__((ext_vector_type(4)));
typedef bf16_t bf16x2 __attribute__((ext_vector_type(2)));
typedef float f32x4 __attribute__((ext_vector_type(4)));
typedef float f32x2 __attribute__((ext_vector_type(2)));

// ---------------------------------------------------------------- CSR build
__global__ void hist_k(const int* __restrict__ dst, int* __restrict__ deg, int E) {
    int e = blockIdx.x * 256 + threadIdx.x;
    if (e < E) atomicAdd(&deg[dst[e]], 1);
}

__global__ __launch_bounds__(1024) void scan_k(const int* __restrict__ deg,
                                               int* __restrict__ offs,
                                               int* __restrict__ cursor, int n) {
    __shared__ int s_ws[16];
    int tid = threadIdx.x;
    int lane = tid & 63, w = tid >> 6;
    int carry = 0;
    for (int base = 0; base < n; base += 1024) {
        int i = base + tid;
        int v = (i < n) ? deg[i] : 0;
        int x = v;
        #pragma unroll
        for (int off = 1; off < 64; off <<= 1) {
            int t = __shfl_up(x, off);
            if (lane >= off) x += t;
        }
        if (lane == 63) s_ws[w] = x;
        __syncthreads();
        if (tid < 16) {
            int y = s_ws[tid];
            #pragma unroll
            for (int off = 1; off < 16; off <<= 1) {
                int t = __shfl_up(y, off);
                if (tid >= off) y += t;
            }
            s_ws[tid] = y;
        }
        __syncthreads();
        int wbase = (w > 0) ? s_ws[w - 1] : 0;
        int ex = carry + wbase + x - v;
        if (i < n) { offs[i] = ex; cursor[i] = ex; }
        carry += s_ws[15];
        __syncthreads();
    }
    if (tid == 0) offs[n] = carry;
}

__global__ void scatter_k(const int* __restrict__ src, const int* __restrict__ dst,
                          int* __restrict__ cursor, int* __restrict__ csr_src,
                          int* __restrict__ csr_eid, int E) {
    int e = blockIdx.x * 256 + threadIdx.x;
    if (e < E) {
        int d = dst[e];
        int p = atomicAdd(&cursor[d], 1);
        csr_src[p] = src[e];
        csr_eid[p] = e;
    }
}

// --------------------------------------------- weight transpose + bf16 cast
__global__ __launch_bounds__(256) void wt_k(const float* __restrict__ W,
                                            bf16_t* __restrict__ Bt, int K, int N) {
    __shared__ float t[32][33];
    int k0 = blockIdx.y * 32, n0 = blockIdx.x * 32;
    int tx = threadIdx.x & 31, ty = threadIdx.x >> 5;
    for (int i = ty; i < 32; i += 8) t[i][tx] = W[(size_t)(k0 + i) * N + n0 + tx];
    __syncthreads();
    for (int i = ty; i < 32; i += 8)
        Bt[(size_t)(n0 + i) * K + k0 + tx] = (bf16_t)t[tx][i];
}

// ---- layer-3 fused weight: Bt[n][k] (128 x 1792), k<1536: stacked W3/6; else lw3
__global__ void w3s_k(const float* __restrict__ W3, const float* __restrict__ lw3,
                      bf16_t* __restrict__ Bt) {
    int id = blockIdx.x * 256 + threadIdx.x;  // 128*1792 = 229376 -> 896 blocks
    if (id >= 128 * 1792) return;
    int n = id / 1792, k = id - n * 1792;
    float v;
    if (k < 1536) {
        int h = k >> 8, c = k & 255;
        v = W3[(size_t)c * 768 + h * 128 + n] * (1.f / 6.f);
    } else {
        int c = k - 1536;
        v = lw3[(size_t)c * 128 + n];
    }
    Bt[id] = (bf16_t)v;
}

// ---- layer-1 fused weight B (40 x 256, f32): block-diag W1 per head + lw1
__global__ void b40_k(const float* __restrict__ W1, const float* __restrict__ lw1,
                      float* __restrict__ B) {
    int id = blockIdx.x * 256 + threadIdx.x;  // 40*256 = 10240 -> 40 blocks
    if (id >= 40 * 256) return;
    int k = id >> 8, n = id & 255;
    float v;
    if (k < 32) {
        int h = k >> 3, c = k & 7;
        v = ((n >> 6) == h) ? W1[(size_t)c * 256 + n] : 0.f;
    } else {
        int c = k - 32;
        v = lw1[(size_t)c * 256 + n];
    }
    B[id] = v;
}

// ---- folded attention vectors: Va[k][h] = sum_c W[k][h*C+c] * a_s[h][c]
__global__ void va_k(const float* __restrict__ W, const float* __restrict__ a_s,
                     const float* __restrict__ a_d, float* __restrict__ Va,
                     float* __restrict__ Vd, int H, int C) {
    int k = blockIdx.x;
    int lane = threadIdx.x;  // 64
    const float* wr = W + (size_t)k * H * C;
    for (int h = 0; h < H; ++h) {
        float sa = 0.f, sd = 0.f;
        for (int c = lane; c < C; c += 64) {
            float wv = wr[h * C + c];
            sa += wv * a_s[h * C + c];
            sd += wv * a_d[h * C + c];
        }
        #pragma unroll
        for (int m = 32; m; m >>= 1) { sa += __shfl_xor(sa, m); sd += __shfl_xor(sd, m); }
        if (lane == 0) { Va[k * H + h] = sa; Vd[k * H + h] = sd; }
    }
}

__global__ void addb_k(const float* __restrict__ a, const float* __restrict__ b,
                       float* __restrict__ o, int n) {
    int i = blockIdx.x * 256 + threadIdx.x;
    if (i < n) o[i] = a[i] + b[i];
}

// ---------------------------------------------------------------- fp32 GEMM
template <typename OUT>
__global__ __launch_bounds__(256) void gemm_k(const float* __restrict__ A,
                                              const float* __restrict__ B,
                                              OUT* __restrict__ C,
                                              const float* __restrict__ bias,
                                              int M, int N, int K, int relu) {
    __shared__ float As[16][65];
    __shared__ float Bs[16][64];
    int tid = threadIdx.x;
    int tx = tid & 15, ty = tid >> 4;
    int row0 = blockIdx.y * 64, col0 = blockIdx.x * 64;
    float acc[4][4] = {};
    for (int k0 = 0; k0 < K; k0 += 16) {
        #pragma unroll
        for (int i = 0; i < 4; ++i) {
            int idx = tid + i * 256;
            int m = idx >> 4, kk = idx & 15;
            int gm = row0 + m, gk = k0 + kk;
            As[kk][m] = (gm < M && gk < K) ? A[(size_t)gm * K + gk] : 0.f;
        }
        #pragma unroll
        for (int i = 0; i < 4; ++i) {
            int idx = tid + i * 256;
            int kk = idx >> 6, n = idx & 63;
            int gk = k0 + kk, gn = col0 + n;
            Bs[kk][n] = (gk < K && gn < N) ? B[(size_t)gk * N + gn] : 0.f;
        }
        __syncthreads();
        #pragma unroll
        for (int kk = 0; kk < 16; ++kk) {
            float a[4], b[4];
            #pragma unroll
            for (int i = 0; i < 4; ++i) a[i] = As[kk][ty * 4 + i];
            #pragma unroll
            for (int j = 0; j < 4; ++j) b[j] = Bs[kk][tx * 4 + j];
            #pragma unroll
            for (int i = 0; i < 4; ++i)
                #pragma unroll
                for (int j = 0; j < 4; ++j) acc[i][j] += a[i] * b[j];
        }
        __syncthreads();
    }
    #pragma unroll
    for (int i = 0; i < 4; ++i) {
        int gm = row0 + ty * 4 + i;
        if (gm >= M) continue;
        #pragma unroll
        for (int j = 0; j < 4; ++j) {
            int gn = col0 + tx * 4 + j;
            if (gn < N) {
                float r = acc[i][j] + (bias ? bias[gn] : 0.f);
                if (relu) r = fmaxf(r, 0.f);
                C[(size_t)gm * N + gn] = (OUT)r;
            }
        }
    }
}

// --------------- bf16 MFMA GEMM, 128x64 tiles (balanced grid for small N).
// 4 waves; wave owns rows [wave*32, wave*32+32) x all 64 cols. Optional fused
// attention-score epilogue: block's 64 cols = exactly one head (Ch==64).
template <typename OUT>
__global__ __launch_bounds__(256) void gemm_bf16_hn_k(
    const bf16_t* __restrict__ A, const bf16_t* __restrict__ Bt,
    OUT* __restrict__ C, const float* __restrict__ bias, int M, int N, int K,
    const float* __restrict__ asv, const float* __restrict__ adv,
    float* __restrict__ as_o, float* __restrict__ ad_o, int H) {
    __shared__ bf16_t As[128][40];
    __shared__ bf16_t Bs[64][40];
    int tid = threadIdx.x;
    int row0 = blockIdx.y * 128, col0 = blockIdx.x * 64;
    int wave = tid >> 6, lane = tid & 63, quad = lane >> 4, l16 = lane & 15;
    f32x4 acc[2][4] = {};
    int sr = tid >> 2;
    int sc = (tid & 3) * 8;
    for (int k0 = 0; k0 < K; k0 += 32) {
        #pragma unroll
        for (int half = 0; half < 2; ++half) {
            int r = sr + half * 64;
            int gm = row0 + r;
            bf16x8 v = {};
            if (gm < M) v = *(const bf16x8*)&A[(size_t)gm * K + k0 + sc];
            *(bf16x8*)&As[r][sc] = v;
        }
        {
            int gn = col0 + sr;
            bf16x8 w = {};
            if (gn < N) w = *(const bf16x8*)&Bt[(size_t)gn * K + k0 + sc];
            *(bf16x8*)&Bs[sr][sc] = w;
        }
        __syncthreads();
        bf16x8 af[2], bfr[4];
        #pragma unroll
        for (int i = 0; i < 2; ++i)
            af[i] = *(const bf16x8*)&As[wave * 32 + i * 16 + l16][quad * 8];
        #pragma unroll
        for (int j = 0; j < 4; ++j)
            bfr[j] = *(const bf16x8*)&Bs[j * 16 + l16][quad * 8];
        #pragma unroll
        for (int i = 0; i < 2; ++i)
            #pragma unroll
            for (int j = 0; j < 4; ++j)
                acc[i][j] = __builtin_amdgcn_mfma_f32_16x16x32_bf16(af[i], bfr[j],
                                                                   acc[i][j], 0, 0, 0);
        __syncthreads();
    }
    #pragma unroll
    for (int i = 0; i < 2; ++i) {
        int base_m = row0 + wave * 32 + i * 16 + quad * 4;
        #pragma unroll
        for (int j = 0; j < 4; ++j) {
            int gn = col0 + j * 16 + l16;
            float bv = bias ? bias[gn] : 0.f;
            #pragma unroll
            for (int r = 0; r < 4; ++r) {
                int gm = base_m + r;
                if (gm < M) C[(size_t)gm * N + gn] = (OUT)(acc[i][j][r] + bv);
            }
        }
    }
    if (asv) {
        int hd = col0 >> 6;  // Ch == 64
        float av[4], dv[4];
        #pragma unroll
        for (int j = 0; j < 4; ++j) {
            int ca = col0 + j * 16 + l16;
            av[j] = asv[ca];
            dv[j] = adv[ca];
        }
        #pragma unroll
        for (int i = 0; i < 2; ++i) {
            float sp[4] = {}, sd[4] = {};
            #pragma unroll
            for (int j = 0; j < 4; ++j)
                #pragma unroll
                for (int r = 0; r < 4; ++r) {
                    sp[r] += acc[i][j][r] * av[j];
                    sd[r] += acc[i][j][r] * dv[j];
                }
            #pragma unroll
            for (int m = 1; m < 16; m <<= 1)
                #pragma unroll
                for (int r = 0; r < 4; ++r) {
                    sp[r] += __shfl_xor(sp[r], m);
                    sd[r] += __shfl_xor(sd[r], m);
                }
            if (l16 == 0) {
                #pragma unroll
                for (int r = 0; r < 4; ++r) {
                    int gm = row0 + wave * 32 + i * 16 + quad * 4 + r;
                    if (gm < M) {
                        as_o[gm * H + hd] = sp[r];
                        ad_o[gm * H + hd] = sd[r];
                    }
                }
            }
        }
    }
}

// ----------------- thin-N bf16 MFMA GEMM: BM=32, BN=64, direct write + relu
__global__ __launch_bounds__(256) void gemm_bf16_thin_k(
    const bf16_t* __restrict__ A, const bf16_t* __restrict__ Bt,
    float* __restrict__ C, const float* __restrict__ bias, int M, int N, int K) {
    __shared__ bf16_t As[32][40];
    __shared__ bf16_t Bs[64][40];
    int tid = threadIdx.x;
    int row0 = blockIdx.y * 32, col0 = blockIdx.x * 64;
    int wave = tid >> 6, lane = tid & 63, quad = lane >> 4, l16 = lane & 15;
    int wr = wave & 1;          // row-tile 0/1 (16 rows each)
    int wc = wave >> 1;         // col-half 0/1 (32 cols each)
    f32x4 acc[2] = {};
    int ar = tid >> 2, ac = (tid & 3) * 8;   // staging coords
    for (int k0 = 0; k0 < K; k0 += 32) {
        if (tid < 128) {
            int gm = row0 + ar;
            bf16x8 v = {};
            if (gm < M) v = *(const bf16x8*)&A[(size_t)gm * K + k0 + ac];
            *(bf16x8*)&As[ar][ac] = v;
        }
        *(bf16x8*)&Bs[ar][ac] = *(const bf16x8*)&Bt[(size_t)(col0 + ar) * K + k0 + ac];
        __syncthreads();
        bf16x8 af = *(const bf16x8*)&As[wr * 16 + l16][quad * 8];
        #pragma unroll
        for (int j = 0; j < 2; ++j) {
            bf16x8 bf = *(const bf16x8*)&Bs[wc * 32 + j * 16 + l16][quad * 8];
            acc[j] = __builtin_amdgcn_mfma_f32_16x16x32_bf16(af, bf, acc[j], 0, 0, 0);
        }
        __syncthreads();
    }
    #pragma unroll
    for (int j = 0; j < 2; ++j) {
        int gn = col0 + wc * 32 + j * 16 + l16;
        float bv = bias[gn];
        #pragma unroll
        for (int r = 0; r < 4; ++r) {
            int gm = row0 + wr * 16 + quad * 4 + r;
            if (gm < M) C[(size_t)gm * N + gn] = fmaxf(acc[j][r] + bv, 0.f);
        }
    }
}

__device__ __forceinline__ float leaky02(float v) { return v > 0.f ? v : 0.2f * v; }

// ------------------------------- layer-1 scores: as[j][h] = x[j]·Va1[:,h]
__global__ void asad1_k(const float* __restrict__ x, const float* __restrict__ Va,
                        const float* __restrict__ Vd, float* __restrict__ as_,
                        float* __restrict__ ad_, int N) {
    int idx = blockIdx.x * 256 + threadIdx.x;
    if (idx >= N * 4) return;
    int j = idx >> 2, h = idx & 3;
    const float* xr = x + (size_t)j * 8;
    float sa = 0.f, sd = 0.f;
    #pragma unroll
    for (int c = 0; c < 8; ++c) {
        sa += xr[c] * Va[c * 4 + h];
        sd += xr[c] * Vd[c * 4 + h];
    }
    as_[idx] = sa;
    ad_[idx] = sd;
}

// ------------------------------- layer-3 scores: as[j][h] = xb[j]·Va3[:,h]
__global__ void asad3_k(const bf16_t* __restrict__ xb, const float* __restrict__ Va,
                        const float* __restrict__ Vd, float* __restrict__ as_,
                        float* __restrict__ ad_) {
    int j = blockIdx.x;
    int lane = threadIdx.x;  // 64
    bf16x4 v = *(const bf16x4*)&xb[(size_t)j * 256 + lane * 4];
    float sa[6] = {}, sd[6] = {};
    #pragma unroll
    for (int i = 0; i < 4; ++i) {
        int k = lane * 4 + i;
        float xv = (float)v[i];
        #pragma unroll
        for (int h = 0; h < 6; ++h) {
            sa[h] += xv * Va[k * 6 + h];
            sd[h] += xv * Vd[k * 6 + h];
        }
    }
    #pragma unroll
    for (int h = 0; h < 6; ++h) {
        float a = sa[h], d = sd[h];
        #pragma unroll
        for (int m = 32; m; m >>= 1) { a += __shfl_xor(a, m); d += __shfl_xor(d, m); }
        if (lane == 0) { as_[j * 6 + h] = a; ad_[j * 6 + h] = d; }
    }
}

// ---------------- layer-1 aggregation in input space (8 ch, 4 heads) -> z1[40]
__global__ __launch_bounds__(256) void agg_z1_k(
    const float* __restrict__ x, const float* __restrict__ as_,
    const float* __restrict__ ad_, const int* __restrict__ offs,
    const int* __restrict__ csr_src, float* __restrict__ z1) {
    int j = blockIdx.x * 4 + (threadIdx.x >> 6);
    int t = threadIdx.x & 63;
    int e_l = t >> 3, c = t & 7;
    int o0 = offs[j], deg = offs[j + 1] - o0;
    float adj0 = ad_[j * 4 + 0], adj1 = ad_[j * 4 + 1];
    float adj2 = ad_[j * 4 + 2], adj3 = ad_[j * 4 + 3];
    float acc[4] = {}, ws[4] = {};
    for (int e0 = 0; e0 < deg; e0 += 8) {
        int ne = min(8, deg - e0);
        if (e_l < ne) {
            int s = csr_src[o0 + e0 + e_l];
            float xv = x[(size_t)s * 8 + c];
            f32x4 a = *(const f32x4*)&as_[s * 4];
            float w0 = __expf(leaky02(a[0] + adj0));
            float w1 = __expf(leaky02(a[1] + adj1));
            float w2 = __expf(leaky02(a[2] + adj2));
            float w3 = __expf(leaky02(a[3] + adj3));
            acc[0] += w0 * xv; acc[1] += w1 * xv;
            acc[2] += w2 * xv; acc[3] += w3 * xv;
            ws[0] += w0; ws[1] += w1; ws[2] += w2; ws[3] += w3;
        }
    }
    #pragma unroll
    for (int m = 8; m < 64; m <<= 1)
        #pragma unroll
        for (int h = 0; h < 4; ++h) {
            acc[h] += __shfl_xor(acc[h], m);
            ws[h] += __shfl_xor(ws[h], m);
        }
    if (e_l == 0) {
        #pragma unroll
        for (int h = 0; h < 4; ++h)
            z1[(size_t)j * 40 + h * 8 + c] = acc[h] / (ws[h] + 1e-16f);
        z1[(size_t)j * 40 + 32 + c] = x[(size_t)j * 8 + c];
    }
}

// ------------------------------------------- aggregation, concat (H=4,C=64)
// (layer 2 only) single-pass no-max softmax, 8 edge-groups x 32 chunk-threads.
__global__ __launch_bounds__(256) void agg_concat_k(
    const bf16_t* __restrict__ h, const float* __restrict__ as_,
    const float* __restrict__ ad_, const int* __restrict__ offs,
    const int* __restrict__ csr_src, const float* __restrict__ lin,
    const float* __restrict__ bgat, bf16_t* __restrict__ xb) {
    int j = blockIdx.x;
    int tid = threadIdx.x;  // 256
    int o0 = offs[j], deg = offs[j + 1] - o0;
    __shared__ int s_src[64];
    __shared__ float s_adj[4];
    __shared__ float s_ws[8][4];
    __shared__ float s_inv[4];
    __shared__ float s_red[8][256];
    if (tid < 4) s_adj[tid] = ad_[j * 4 + tid];
    int g = tid >> 5;
    int u = tid & 31;
    int myh = u >> 3;
    const char* hbase = (const char*)h + u * 16;
    f32x4 acc0 = {}, acc1 = {};
    float wsum = 0.f;
    for (int e0 = 0; e0 < deg; e0 += 64) {
        int ne = min(64, deg - e0);
        if (tid < ne) s_src[tid] = csr_src[o0 + e0 + tid];
        __syncthreads();
        float adj = s_adj[myh];
        #pragma unroll 2
        for (int e = g; e < ne; e += 8) {
            int s = s_src[e];
            float w = __expf(leaky02(as_[s * 4 + myh] + adj));
            bf16x8 v = *(const bf16x8*)(hbase + (size_t)s * 512);
            wsum += w;
            #pragma unroll
            for (int i = 0; i < 4; ++i) acc0[i] += w * (float)v[i];
            #pragma unroll
            for (int i = 0; i < 4; ++i) acc1[i] += w * (float)v[4 + i];
        }
        __syncthreads();
    }
    if ((u & 7) == 0) s_ws[g][myh] = wsum;
    *(f32x4*)&s_red[g][u * 8] = acc0;
    *(f32x4*)&s_red[g][u * 8 + 4] = acc1;
    __syncthreads();
    if (tid < 4) {
        float d = 0.f;
        #pragma unroll
        for (int g2 = 0; g2 < 8; ++g2) d += s_ws[g2][tid];
        s_inv[tid] = 1.f / (d + 1e-16f);
    }
    __syncthreads();
    {
        int c = tid;
        float s = 0.f;
        #pragma unroll
        for (int g2 = 0; g2 < 8; ++g2) s += s_red[g2][c];
        float v = fmaxf(s * s_inv[c >> 6] + bgat[c] + lin[(size_t)j * 256 + c], 0.f);
        xb[(size_t)j * 256 + c] = (bf16_t)v;
    }
}

// --------- layer-3 aggregation in xb space: z[j] = [z_h (6x256), xb[j] (256)]
// 192 threads = 6 heads x 32 chunks; per-thread complete wsum, ~2 KB LDS.
__global__ __launch_bounds__(192) void agg_z3_k(
    const bf16_t* __restrict__ xb, const float* __restrict__ as_,
    const float* __restrict__ ad_, const int* __restrict__ offs,
    const int* __restrict__ csr_src, const int* __restrict__ csr_eid,
    bf16_t* __restrict__ z, float* __restrict__ att) {
    int j = blockIdx.x;
    int tid = threadIdx.x;  // 192
    int o0 = offs[j], deg = offs[j + 1] - o0;
    __shared__ float s_adj[6];
    __shared__ int s_src[64];
    __shared__ float s_w[64 * 6];
    __shared__ float s_inv[6];
    if (tid < 6) s_adj[tid] = ad_[j * 6 + tid];
    __syncthreads();
    int h = tid >> 5;          // head 0..5
    int c = tid & 31;          // 16-B chunk -> channels c*8..c*8+7
    const char* xbase = (const char*)xb + c * 16;
    f32x4 a0 = {}, a1 = {};
    float wsum = 0.f;
    for (int e0 = 0; e0 < deg; e0 += 64) {
        int ne = min(64, deg - e0);
        #pragma unroll
        for (int base = 0; base < 2; ++base) {
            int idx = tid + base * 192;
            if (idx < ne * 6) {
                int e = idx / 6, hh = idx - e * 6;
                int s = csr_src[o0 + e0 + e];
                if (hh == 0) s_src[e] = s;
                s_w[idx] = __expf(leaky02(as_[s * 6 + hh] + s_adj[hh]));
            }
        }
        __syncthreads();
        #pragma unroll 4
        for (int e = 0; e < ne; ++e) {
            int s = s_src[e];
            float w = s_w[e * 6 + h];
            bf16x8 v = *(const bf16x8*)(xbase + (size_t)s * 512);
            wsum += w;
            #pragma unroll
            for (int i = 0; i < 4; ++i) a0[i] += w * (float)v[i];
            #pragma unroll
            for (int i = 0; i < 4; ++i) a1[i] += w * (float)v[4 + i];
        }
        __syncthreads();
    }
    float inv = 1.f / (wsum + 1e-16f);
    {
        bf16x8 o;
        #pragma unroll
        for (int i = 0; i < 4; ++i) o[i] = (bf16_t)(a0[i] * inv);
        #pragma unroll
        for (int i = 0; i < 4; ++i) o[4 + i] = (bf16_t)(a1[i] * inv);
        *(bf16x8*)&z[(size_t)j * 1792 + h * 256 + c * 8] = o;
    }
    if (tid < 32)
        *(bf16x8*)&z[(size_t)j * 1792 + 1536 + tid * 8] =
            *(const bf16x8*)&xb[(size_t)j * 256 + tid * 8];
    if (c == 0) s_inv[h] = inv;
    __syncthreads();
    for (int idx = tid; idx < deg * 6; idx += 192) {
        int e = idx / 6, hh = idx - e * 6;
        int p = o0 + e;
        int s = csr_src[p];
        att[(size_t)csr_eid[p] * 6 + hh] =
            __expf(leaky02(as_[s * 6 + hh] + s_adj[hh])) * s_inv[hh];
    }
}

// ---------------------------------------------------------------- BatchNorm
__global__ void bn_stats_k(const float* __restrict__ y, float* __restrict__ sums, int N) {
    int c = threadIdx.x;  // 128
    float s = 0.f, q = 0.f;
    for (int r = blockIdx.x; r < N; r += gridDim.x) {
        float v = y[(size_t)r * 128 + c];
        s += v;
        q += v * v;
    }
    atomicAdd(&sums[c], s);
    atomicAdd(&sums[128 + c], q);
}
__global__ void bn_scale_k(const float* __restrict__ sums, const float* __restrict__ gamma,
                           const float* __restrict__ beta, float* __restrict__ scale,
                           float* __restrict__ shift, int N) {
    int c = threadIdx.x;
    float mu = sums[c] / (float)N;
    float var = fmaxf(sums[128 + c] / (float)N - mu * mu, 0.f);
    float inv = rsqrtf(var + 1e-5f) * gamma[c];
    scale[c] = inv;
    shift[c] = beta[c] - mu * inv;
}

// ---------------------------------------------------------------- max pool
__device__ __forceinline__ unsigned f2key(float f) {
    unsigned b = __float_as_uint(f);
    return (b & 0x80000000u) ? ~b : (b | 0x80000000u);
}
__global__ void pool_init_k(unsigned* __restrict__ pool_u) {
    int i = blockIdx.x * 256 + threadIdx.x;
    if (i < N_GRAPHS * 128) pool_u[i] = f2key(-3.402823466e38f * 2.0f);
}
__global__ void norm_pool_k(const float* __restrict__ y, const float* __restrict__ scale,
                            const float* __restrict__ shift, const int* __restrict__ batch,
                            unsigned* __restrict__ pool_u, int N) {
    int idx = blockIdx.x * 256 + threadIdx.x;
    if (idx >= N * 128) return;
    int n = idx >> 7, c = idx & 127;
    float v = y[idx] * scale[c] + shift[c];
    atomicMax(&pool_u[batch[n] * 128 + c], f2key(v));
}
__global__ void pool_write_k(const unsigned* __restrict__ pool_u, float* __restrict__ out) {
    int i = blockIdx.x * 256 + threadIdx.x;
    if (i < N_GRAPHS * 128) {
        unsigned u = pool_u[i];
        unsigned b = (u & 0x80000000u) ? (u & 0x7FFFFFFFu) : ~u;
        out[i] = __uint_as_float(b);
    }
}

// ================================================================ launcher
extern "C" void kernel_launch(void* const* d_in, const int* in_sizes, int n_in,
                              void* d_out, int out_size, void* d_ws, size_t ws_size,
                              hipStream_t stream) {
    const int N = N_NODES, E = N_EDGES;
    const float* x_ppi = (const float*)d_in[0];
    const int* edge = (const int*)d_in[1];
    const int* batch = (const int*)d_in[2];
    const float* W1 = (const float*)d_in[3];
    const float* a_src1 = (const float*)d_in[4];
    const float* a_dst1 = (const float*)d_in[5];
    const float* b_gat1 = (const float*)d_in[6];
    const float* lw1 = (const float*)d_in[7];
    const float* lb1 = (const float*)d_in[8];
    const float* W2 = (const float*)d_in[9];
    const float* a_src2 = (const float*)d_in[10];
    const float* a_dst2 = (const float*)d_in[11];
    const float* b_gat2 = (const float*)d_in[12];
    const float* lw2 = (const float*)d_in[13];
    const float* lb2 = (const float*)d_in[14];
    const float* W3 = (const float*)d_in[15];
    const float* a_src3 = (const float*)d_in[16];
    const float* a_dst3 = (const float*)d_in[17];
    const float* b_gat3 = (const float*)d_in[18];
    const float* lw3 = (const float*)d_in[19];
    const float* lb3 = (const float*)d_in[20];
    const float* bn_gamma = (const float*)d_in[21];
    const float* bn_beta = (const float*)d_in[22];

    const int* src = edge;
    const int* dst = edge + E;

    size_t off = 0;
    auto alloc = [&](size_t bytes) {
        size_t o = off;
        off = (off + bytes + 255) & ~(size_t)255;
        return o;
    };
    char* ws = (char*)d_ws;
    bf16_t* xb = (bf16_t*)(ws + alloc((size_t)N * 256 * 2));
    bf16_t* zbig = (bf16_t*)(ws + alloc((size_t)N * 1792 * 2)); // union: hb (layer2) / z3
    bf16_t* hb = zbig;
    bf16_t* z3 = zbig;
    float* lin = (float*)(ws + alloc((size_t)N * 256 * 4));      // layer-2 lin; reused as y
    float* z1 = (float*)(ws + alloc((size_t)N * 40 * 4));
    float* as_ = (float*)(ws + alloc((size_t)N * 6 * 4));
    float* ad_ = (float*)(ws + alloc((size_t)N * 6 * 4));
    int* deg = (int*)(ws + alloc((size_t)(N + 1) * 4));
    int* offs = (int*)(ws + alloc((size_t)(N + 1) * 4));
    int* cursor = (int*)(ws + alloc((size_t)(N + 1) * 4));
    int* csr_src = (int*)(ws + alloc((size_t)E * 4));
    int* csr_eid = (int*)(ws + alloc((size_t)E * 4));
    bf16_t* Wt2 = (bf16_t*)(ws + alloc((size_t)256 * 256 * 2));
    bf16_t* lwt2 = (bf16_t*)(ws + alloc((size_t)256 * 256 * 2));
    bf16_t* Bt3s = (bf16_t*)(ws + alloc((size_t)128 * 1792 * 2));
    float* B40 = (float*)(ws + alloc((size_t)40 * 256 * 4));
    float* Va1 = (float*)(ws + alloc(8 * 4 * 4));
    float* Vd1 = (float*)(ws + alloc(8 * 4 * 4));
    float* Va3 = (float*)(ws + alloc(256 * 6 * 4));
    float* Vd3 = (float*)(ws + alloc(256 * 6 * 4));
    float* bias1s = (float*)(ws + alloc(256 * 4));
    float* bias3s = (float*)(ws + alloc(128 * 4));
    float* bn_sums = (float*)(ws + alloc(256 * 4));
    float* bn_scale = (float*)(ws + alloc(128 * 4));
    float* bn_shift = (float*)(ws + alloc(128 * 4));
    unsigned* pool_u = (unsigned*)(ws + alloc((size_t)N_GRAPHS * 128 * 4));

    float* out_pool = (float*)d_out;
    float* out_att = (float*)d_out + N_GRAPHS * 128;

    // ---- CSR + weight prep (independent)
    hipMemsetAsync(deg, 0, (size_t)N * 4, stream);
    hist_k<<<(E + 255) / 256, 256, 0, stream>>>(dst, deg, E);
    scan_k<<<1, 1024, 0, stream>>>(deg, offs, cursor, N);
    scatter_k<<<(E + 255) / 256, 256, 0, stream>>>(src, dst, cursor, csr_src, csr_eid, E);
    wt_k<<<dim3(8, 8), 256, 0, stream>>>(W2, Wt2, 256, 256);
    wt_k<<<dim3(8, 8), 256, 0, stream>>>(lw2, lwt2, 256, 256);
    w3s_k<<<896, 256, 0, stream>>>(W3, lw3, Bt3s);
    b40_k<<<40, 256, 0, stream>>>(W1, lw1, B40);
    va_k<<<8, 64, 0, stream>>>(W1, a_src1, a_dst1, Va1, Vd1, 4, 64);
    va_k<<<256, 64, 0, stream>>>(W3, a_src3, a_dst3, Va3, Vd3, 6, 128);
    addb_k<<<1, 256, 0, stream>>>(lb1, b_gat1, bias1s, 256);
    addb_k<<<1, 128, 0, stream>>>(lb3, b_gat3, bias3s, 128);

    // ---- Layer 1: aggregate in 8-ch input space, then one K=40 fused GEMM
    asad1_k<<<(N * 4 + 255) / 256, 256, 0, stream>>>(x_ppi, Va1, Vd1, as_, ad_, N);
    agg_z1_k<<<N / 4, 256, 0, stream>>>(x_ppi, as_, ad_, offs, csr_src, z1);
    gemm_k<bf16_t><<<dim3(4, 313), 256, 0, stream>>>(z1, B40, xb, bias1s, N, 256, 40, 1);

    // ---- Layer 2 (256 -> 256, bf16 MFMA, 128x64 tiles); as/ad fused epilogue
    gemm_bf16_hn_k<bf16_t><<<dim3(4, 157), 256, 0, stream>>>(xb, Wt2, hb, nullptr, N, 256, 256,
                                                             a_src2, a_dst2, as_, ad_, 4);
    gemm_bf16_hn_k<float><<<dim3(4, 157), 256, 0, stream>>>(xb, lwt2, lin, lb2, N, 256, 256,
                                                            nullptr, nullptr, nullptr, nullptr,
                                                            0);
    agg_concat_k<<<N, 256, 0, stream>>>(hb, as_, ad_, offs, csr_src, lin, b_gat2, xb);

    // ---- Layer 3: scores from folded Va3/Vd3, aggregate xb space, thin GEMM
    float* y = lin;  // reuse (free after agg_concat_k)
    asad3_k<<<N, 64, 0, stream>>>(xb, Va3, Vd3, as_, ad_);
    agg_z3_k<<<N, 192, 0, stream>>>(xb, as_, ad_, offs, csr_src, csr_eid, z3, out_att);
    gemm_bf16_thin_k<<<dim3(2, 625), 256, 0, stream>>>(z3, Bt3s, y, bias3s, N, 128, 1792);

    // ---- BatchNorm (training stats, fused sum+sumsq pass)
    hipMemsetAsync(bn_sums, 0, 256 * 4, stream);
    bn_stats_k<<<160, 128, 0, stream>>>(y, bn_sums, N);
    bn_scale_k<<<1, 128, 0, stream>>>(bn_sums, bn_gamma, bn_beta, bn_scale, bn_shift, N);

    // ---- normalize + global max pool
    pool_init_k<<<(N_GRAPHS * 128 + 255) / 256, 256, 0, stream>>>(pool_u);
    norm_pool_k<<<((size_t)N * 128 + 255) / 256, 256, 0, stream>>>(y, bn_scale, bn_shift, batch,
                                                                   pool_u, N);
    pool_write_k<<<(N_GRAPHS * 128 + 255) / 256, 256, 0, stream>>>(pool_u, out_pool);
}